// Round 1
// baseline (166.458 us; speedup 1.0000x reference)
//
#include <hip/hip_runtime.h>
#include <math.h>

#define EPS 1e-6f
#define C 1604
#define B 16384
#define C4 401          // C/4, exact (1604 = 4*401)
#define BLOCK 256

// One block per batch row. Each thread owns up to 2 float4 chunks of the
// logits row (kept in registers across both passes) and the matching chunks
// of s[t, :]. Two block reductions: max, then seesaw denominator.
__global__ __launch_bounds__(BLOCK) void seesaw_row_kernel(
    const float* __restrict__ logits,
    const float* __restrict__ s,
    const int*   __restrict__ targets,
    float*       __restrict__ block_loss)
{
    const int b    = blockIdx.x;
    const int tid  = threadIdx.x;
    const int wave = tid >> 6;
    const int lane = tid & 63;
    const int t    = targets[b];

    const float4* lrow = (const float4*)(logits + (size_t)b * C);
    const float4* srow = (const float4*)(s + (size_t)t * C);

    const bool has1 = (tid + BLOCK) < C4;   // tid < 145 owns a second chunk

    float4 v0 = lrow[tid];                  // tid in [0,255] < 401: always valid
    float4 v1 = has1 ? lrow[tid + BLOCK]
                     : make_float4(-INFINITY, -INFINITY, -INFINITY, -INFINITY);

    // ---- pass 1: row max ----
    float m = fmaxf(fmaxf(v0.x, v0.y), fmaxf(v0.z, v0.w));
    m = fmaxf(m, fmaxf(fmaxf(v1.x, v1.y), fmaxf(v1.z, v1.w)));

    #pragma unroll
    for (int off = 32; off > 0; off >>= 1)
        m = fmaxf(m, __shfl_down(m, off, 64));

    __shared__ float swav[4];
    __shared__ float s_m;
    __shared__ float s_numt;
    if (lane == 0) swav[wave] = m;
    __syncthreads();
    if (tid == 0)
        s_m = fmaxf(fmaxf(swav[0], swav[1]), fmaxf(swav[2], swav[3]));
    __syncthreads();
    m = s_m;

    // numerator at the target column (owner thread already has it in regs)
    const int t4 = t >> 2;
    if (t4 == tid || (has1 && t4 == tid + BLOCK)) {
        float4 v = (t4 == tid) ? v0 : v1;
        int r = t & 3;
        float lt = (r == 0) ? v.x : (r == 1) ? v.y : (r == 2) ? v.z : v.w;
        s_numt = __expf(lt - m);
    }

    // ---- pass 2: denom = sum_{j!=t} exp(l_j - m) * s[t,j]  +  exp(l_t - m) ----
    float4 sr0 = srow[tid];
    float4 sr1 = has1 ? srow[tid + BLOCK] : make_float4(0.f, 0.f, 0.f, 0.f);

    float partial = 0.f;
    {
        int j = tid << 2;
        partial += __expf(v0.x - m) * ((j    ) == t ? 1.0f : sr0.x);
        partial += __expf(v0.y - m) * ((j + 1) == t ? 1.0f : sr0.y);
        partial += __expf(v0.z - m) * ((j + 2) == t ? 1.0f : sr0.z);
        partial += __expf(v0.w - m) * ((j + 3) == t ? 1.0f : sr0.w);
    }
    if (has1) {
        int j = (tid + BLOCK) << 2;
        partial += __expf(v1.x - m) * ((j    ) == t ? 1.0f : sr1.x);
        partial += __expf(v1.y - m) * ((j + 1) == t ? 1.0f : sr1.y);
        partial += __expf(v1.z - m) * ((j + 2) == t ? 1.0f : sr1.z);
        partial += __expf(v1.w - m) * ((j + 3) == t ? 1.0f : sr1.w);
    }

    #pragma unroll
    for (int off = 32; off > 0; off >>= 1)
        partial += __shfl_down(partial, off, 64);
    if (lane == 0) swav[wave] = partial;
    __syncthreads();          // also publishes s_numt

    if (tid == 0) {
        float denom = (swav[0] + swav[1]) + (swav[2] + swav[3]);
        float sigma = s_numt / (denom + EPS);
        block_loss[b] = -logf(sigma + EPS);
    }
}

// Deterministic final mean over 16384 per-row losses (single block).
__global__ __launch_bounds__(BLOCK) void seesaw_reduce_kernel(
    const float* __restrict__ in, float* __restrict__ out)
{
    const int tid = threadIdx.x;
    const float4* in4 = (const float4*)in;
    float acc = 0.f;
    #pragma unroll
    for (int i = tid; i < B / 4; i += BLOCK) {
        float4 v = in4[i];
        acc += (v.x + v.y) + (v.z + v.w);
    }
    #pragma unroll
    for (int off = 32; off > 0; off >>= 1)
        acc += __shfl_down(acc, off, 64);
    __shared__ float sw[4];
    if ((tid & 63) == 0) sw[tid >> 6] = acc;
    __syncthreads();
    if (tid == 0)
        out[0] = ((sw[0] + sw[1]) + (sw[2] + sw[3])) * (1.0f / B);
}

extern "C" void kernel_launch(void* const* d_in, const int* in_sizes, int n_in,
                              void* d_out, int out_size, void* d_ws, size_t ws_size,
                              hipStream_t stream) {
    const float* logits  = (const float*)d_in[0];
    const float* s       = (const float*)d_in[1];
    const int*   targets = (const int*)d_in[2];
    float* out        = (float*)d_out;
    float* block_loss = (float*)d_ws;   // B floats = 64 KB scratch

    seesaw_row_kernel<<<B, BLOCK, 0, stream>>>(logits, s, targets, block_loss);
    seesaw_reduce_kernel<<<1, BLOCK, 0, stream>>>(block_loss, out);
}

// Round 2
// 163.852 us; speedup vs baseline: 1.0159x; 1.0159x over previous
//
#include <hip/hip_runtime.h>
#include <math.h>

#define EPS 1e-6f
#define C 1604
#define B 16384
#define C4 401              // C/4 exact
#define BLOCK 256           // 4 waves -> 4 rows per block
#define ROWS_PER_BLOCK 4
#define TAIL_LANES (C4 - 6 * 64)   // 17

// One WAVE per batch row: no LDS, no __syncthreads, all 14 global loads
// issued up front (s-row address depends only on targets[b], not on the max).
__global__ __launch_bounds__(BLOCK) void seesaw_row_kernel(
    const float* __restrict__ logits,
    const float* __restrict__ s,
    const int*   __restrict__ targets,
    float*       __restrict__ row_loss)
{
    const int wave = threadIdx.x >> 6;
    const int lane = threadIdx.x & 63;
    const int b = blockIdx.x * ROWS_PER_BLOCK + wave;
    const int t = targets[b];            // wave-uniform -> scalar load

    const float4* lrow = (const float4*)(logits + (size_t)b * C);
    const float4* srow = (const float4*)(s + (size_t)t * C);

    // ---- issue ALL loads up front: lane owns chunks lane + 64k, k=0..6 ----
    float4 lv[7], sv[7];
    #pragma unroll
    for (int k = 0; k < 6; ++k) lv[k] = lrow[lane + 64 * k];
    #pragma unroll
    for (int k = 0; k < 6; ++k) sv[k] = srow[lane + 64 * k];
    const bool tail = lane < TAIL_LANES;
    lv[6] = tail ? lrow[lane + 384]
                 : make_float4(-INFINITY, -INFINITY, -INFINITY, -INFINITY);
    sv[6] = tail ? srow[lane + 384] : make_float4(0.f, 0.f, 0.f, 0.f);

    // ---- row max: per-lane then 6-step butterfly ----
    float m = -INFINITY;
    #pragma unroll
    for (int k = 0; k < 7; ++k)
        m = fmaxf(m, fmaxf(fmaxf(lv[k].x, lv[k].y), fmaxf(lv[k].z, lv[k].w)));
    #pragma unroll
    for (int off = 32; off > 0; off >>= 1)
        m = fmaxf(m, __shfl_xor(m, off, 64));

    // ---- denom partial + target-logit capture (reuses the j==t compares) ----
    // denom[b] = sum_j (j==t ? exp(l_j-m) : s[t,j]*exp(l_j-m))
    float p = 0.f;
    float lt_local = 0.f;
    #pragma unroll
    for (int k = 0; k < 7; ++k) {
        const int j = (lane + 64 * k) << 2;
        const bool e0 = (j     == t);
        const bool e1 = (j + 1 == t);
        const bool e2 = (j + 2 == t);
        const bool e3 = (j + 3 == t);
        p += __expf(lv[k].x - m) * (e0 ? 1.f : sv[k].x);
        p += __expf(lv[k].y - m) * (e1 ? 1.f : sv[k].y);
        p += __expf(lv[k].z - m) * (e2 ? 1.f : sv[k].z);
        p += __expf(lv[k].w - m) * (e3 ? 1.f : sv[k].w);
        if (e0) lt_local = lv[k].x;
        if (e1) lt_local = lv[k].y;
        if (e2) lt_local = lv[k].z;
        if (e3) lt_local = lv[k].w;
    }
    #pragma unroll
    for (int off = 32; off > 0; off >>= 1)
        p += __shfl_xor(p, off, 64);

    // broadcast target logit from its owner lane ((t>>2) & 63)
    const float lt = __shfl(lt_local, (t >> 2) & 63, 64);

    if (lane == 0) {
        const float numt  = __expf(lt - m);
        const float sigma = numt / (p + EPS);
        row_loss[b] = -logf(sigma + EPS);
    }
}

// Deterministic final mean over B per-row losses (single block, 1024 threads).
__global__ __launch_bounds__(1024) void seesaw_reduce_kernel(
    const float* __restrict__ in, float* __restrict__ out)
{
    const int tid = threadIdx.x;
    const float4* in4 = (const float4*)in;
    float acc = 0.f;
    #pragma unroll
    for (int i = tid; i < B / 4; i += 1024) {
        float4 v = in4[i];
        acc += (v.x + v.y) + (v.z + v.w);
    }
    #pragma unroll
    for (int off = 32; off > 0; off >>= 1)
        acc += __shfl_xor(acc, off, 64);
    __shared__ float sw[16];
    if ((tid & 63) == 0) sw[tid >> 6] = acc;
    __syncthreads();
    if (tid == 0) {
        float s0 = 0.f;
        #pragma unroll
        for (int w = 0; w < 16; ++w) s0 += sw[w];
        out[0] = s0 * (1.0f / B);
    }
}

extern "C" void kernel_launch(void* const* d_in, const int* in_sizes, int n_in,
                              void* d_out, int out_size, void* d_ws, size_t ws_size,
                              hipStream_t stream) {
    const float* logits  = (const float*)d_in[0];
    const float* s       = (const float*)d_in[1];
    const int*   targets = (const int*)d_in[2];
    float* out      = (float*)d_out;
    float* row_loss = (float*)d_ws;     // B floats = 64 KB scratch

    seesaw_row_kernel<<<B / ROWS_PER_BLOCK, BLOCK, 0, stream>>>(logits, s, targets, row_loss);
    seesaw_reduce_kernel<<<1, 1024, 0, stream>>>(row_loss, out);
}